// Round 1
// baseline (317.598 us; speedup 1.0000x reference)
//
#include <hip/hip_runtime.h>
#include <hip/hip_bf16.h>

typedef unsigned short u16;
typedef unsigned int u32;
typedef __bf16 bf16x8 __attribute__((ext_vector_type(8)));
typedef float f32x4 __attribute__((ext_vector_type(4)));

#define LOG2E 1.4426950408889634f

__device__ __forceinline__ u16 f2bf(float f){
  u32 x = __float_as_uint(f);
  x += 0x7fffu + ((x >> 16) & 1u);   // RTNE
  return (u16)(x >> 16);
}

// ---------------- GroupNorm stats: one block per (b, group) -----------------
// each group = 16 channels x 1024 spatial = 16384 contiguous f32
__global__ __launch_bounds__(256) void gn_stats_k(const float* __restrict__ x,
                                                  float* __restrict__ stats){
  int blk = blockIdx.x;                 // b*32 + g
  const float* p = x + (size_t)blk * 16384;
  int tid = threadIdx.x;
  float s = 0.f, ss = 0.f;
  for (int it = 0; it < 16; ++it){
    f32x4 v = *(const f32x4*)(p + it*1024 + tid*4);
    s  += v.x + v.y + v.z + v.w;
    ss += v.x*v.x + v.y*v.y + v.z*v.z + v.w*v.w;
  }
  __shared__ float rs[256], rss[256];
  rs[tid] = s; rss[tid] = ss; __syncthreads();
  for (int st = 128; st > 0; st >>= 1){
    if (tid < st){ rs[tid] += rs[tid+st]; rss[tid] += rss[tid+st]; }
    __syncthreads();
  }
  if (tid == 0){
    float mean = rs[0] * (1.f/16384.f);
    float var  = rss[0] * (1.f/16384.f) - mean*mean;
    stats[blk*2]   = mean;
    stats[blk*2+1] = rsqrtf(var + 1e-5f);
  }
}

// ------- GroupNorm apply + transpose: ht[b][l][c] bf16 (c contiguous) -------
// one block per (b, 32-wide l-chunk)
__global__ __launch_bounds__(256) void gn_apply_k(const float* __restrict__ x,
                                                  const float* __restrict__ gw,
                                                  const float* __restrict__ gb,
                                                  const float* __restrict__ stats,
                                                  u16* __restrict__ ht){
  int blk = blockIdx.x; int b = blk >> 5, lc = blk & 31;
  int tid = threadIdx.x;
  __shared__ float sm[32], sr[32], sgw[512], sgb[512];
  __shared__ u16 T[32*512];             // [l][c]
  if (tid < 32){ sm[tid] = stats[(b*32+tid)*2]; sr[tid] = stats[(b*32+tid)*2+1]; }
  sgw[tid] = gw[tid]; sgw[tid+256] = gw[tid+256];
  sgb[tid] = gb[tid]; sgb[tid+256] = gb[tid+256];
  __syncthreads();
  const float* xb = x + (size_t)b*512*1024 + lc*32;
  for (int it = 0; it < 16; ++it){
    int idx = it*1024 + tid*4;
    int c = idx >> 5, l0 = idx & 31;
    f32x4 v = *(const f32x4*)(xb + (size_t)c*1024 + l0);
    int g = c >> 4;
    float mu = sm[g], r = sr[g], w = sgw[c], bb = sgb[c];
    T[(l0+0)*512 + c] = f2bf((v.x-mu)*r*w + bb);
    T[(l0+1)*512 + c] = f2bf((v.y-mu)*r*w + bb);
    T[(l0+2)*512 + c] = f2bf((v.z-mu)*r*w + bb);
    T[(l0+3)*512 + c] = f2bf((v.w-mu)*r*w + bb);
  }
  __syncthreads();
  u16* hb = ht + ((size_t)b*1024 + lc*32)*512;
  for (int it = 0; it < 8; ++it){
    int chunk = it*256 + tid;
    int l = chunk >> 6, c8 = (chunk & 63)*8;
    *(uint4*)(hb + (size_t)l*512 + c8) = *(const uint4*)(T + l*512 + c8);
  }
}

// ------ weight prep: conv_w -> bf16, attention scale folded into q,k -------
__global__ __launch_bounds__(256) void prep_w_k(const float* __restrict__ cw,
                                                const float* __restrict__ cb,
                                                u16* __restrict__ wb,
                                                float* __restrict__ biasS){
  int gid = blockIdx.x*256 + threadIdx.x;
  const float SC = 0.35355339059327373f;     // 64^-0.25
  int i4 = gid*4;
  int row = i4 >> 9;                          // 512 per row
  float s = (row < 1024) ? SC : 1.0f;         // q,k rows scaled; v unscaled
  f32x4 v = *(const f32x4*)(cw + i4);
  wb[i4+0] = f2bf(v.x*s); wb[i4+1] = f2bf(v.y*s);
  wb[i4+2] = f2bf(v.z*s); wb[i4+3] = f2bf(v.w*s);
  if (gid < 1536) biasS[gid] = cb[gid] * ((gid < 1024) ? SC : 1.0f);
}

// ------------- QKV GEMM: qkv_t[b][l][o] = ht[b][l][:] . wb[o][:] -----------
// per batch M=1024(l) N=1536(o) K=512(c); 128x128 tile, BK=64, 4 waves (2x2)
__global__ __launch_bounds__(256) void gemm_k(const u16* __restrict__ ht,
                                              const u16* __restrict__ wb,
                                              const float* __restrict__ biasS,
                                              u16* __restrict__ qkv){
  int b  = blockIdx.y;
  int mt = blockIdx.x & 7, nt = blockIdx.x >> 3;
  int m0 = mt*128, n0 = nt*128;
  int tid = threadIdx.x, lane = tid & 63, wid = tid >> 6;
  int wm = wid >> 1, wn = wid & 1;
  int la = lane & 15, hi = lane >> 4;
  __shared__ u16 As[128*64], Bs[128*64];      // row-major, k contiguous
  const u16* Ab = ht + (size_t)b*1024*512;
  f32x4 acc[4][4] = {};
  for (int kt = 0; kt < 8; ++kt){
    for (int i = 0; i < 4; ++i){
      int chunk = i*256 + tid;
      int row = chunk >> 3, c8 = (chunk & 7)*8;
      *(uint4*)(As + chunk*8) = *(const uint4*)(Ab + (size_t)(m0+row)*512 + kt*64 + c8);
      *(uint4*)(Bs + chunk*8) = *(const uint4*)(wb + (size_t)(n0+row)*512 + kt*64 + c8);
    }
    __syncthreads();
    for (int kk = 0; kk < 2; ++kk){
      int ko = kk*32 + hi*8;
      bf16x8 af[4], bf[4];
      for (int mi = 0; mi < 4; ++mi) af[mi] = *(const bf16x8*)(As + (wm*64 + mi*16 + la)*64 + ko);
      for (int ni = 0; ni < 4; ++ni) bf[ni] = *(const bf16x8*)(Bs + (wn*64 + ni*16 + la)*64 + ko);
      for (int mi = 0; mi < 4; ++mi)
        for (int ni = 0; ni < 4; ++ni)
          acc[mi][ni] = __builtin_amdgcn_mfma_f32_16x16x32_bf16(af[mi], bf[ni], acc[mi][ni], 0, 0, 0);
    }
    __syncthreads();
  }
  u16* qb = qkv + (size_t)b*1024*1536;
  for (int ni = 0; ni < 4; ++ni){
    int o = n0 + wn*64 + ni*16 + la;
    float bias = biasS[o];
    for (int mi = 0; mi < 4; ++mi){
      int l = m0 + wm*64 + mi*16 + hi*4;
      for (int r = 0; r < 4; ++r)
        qb[(size_t)(l+r)*1536 + o] = f2bf(acc[mi][ni][r] + bias);
    }
  }
}

// ------------------- fused flash attention + residual ----------------------
// one block per (bh, 64-row t-tile); 4 waves, each owns 16 t-rows
__global__ __launch_bounds__(256) void attn_k(const u16* __restrict__ qkv,
                                              const float* __restrict__ x,
                                              float* __restrict__ out){
  int orig = blockIdx.x;
  int vid = (orig & 7)*256 + (orig >> 3);     // XCD-bijective swizzle (2048%8==0)
  int bh = vid >> 4, tt = vid & 15;
  int b = bh >> 3, hd = bh & 7;
  int t0 = tt*64;
  int tid = threadIdx.x, lane = tid & 63, w = tid >> 6;
  int la = lane & 15, hi = lane >> 4;
  __shared__ u16 Ks[64*64];                   // [s][c]
  __shared__ u16 VT[64*64];                   // [c][s]
  __shared__ u16 P[4*16*64];                  // per-wave [16t][64s]
  __shared__ float a_t[64*66];                // [c][t], padded
  const u16* base = qkv + (size_t)b*1024*1536;
  // Q A-frags in registers (rows t0+w*16+la, 8 contiguous c at hi*8)
  bf16x8 qf[2];
  {
    const u16* qrow = base + (size_t)(t0 + w*16 + la)*1536 + hd*64;
    qf[0] = *(const bf16x8*)(qrow + hi*8);
    qf[1] = *(const bf16x8*)(qrow + 32 + hi*8);
  }
  float mrun[4], lrun[4];
  f32x4 oacc[4] = {};
  for (int r = 0; r < 4; ++r){ mrun[r] = -1e30f; lrun[r] = 0.f; }
  int ko = 512 + hd*64, vo = 1024 + hd*64;
  for (int st = 0; st < 16; ++st){
    int s0 = st*64;
    __syncthreads();                          // previous tile fully consumed
    for (int i = 0; i < 2; ++i){              // stage K linear
      int chunk = i*256 + tid;
      int row = chunk >> 3, c8 = (chunk & 7)*8;
      *(uint4*)(Ks + chunk*8) = *(const uint4*)(base + (size_t)(s0+row)*1536 + ko + c8);
    }
    {                                         // stage V transposed (s-pairs -> b32)
      int sp = tid >> 3, c0 = (tid & 7)*8;
      const u16* vp = base + (size_t)(s0 + sp*2)*1536 + vo + c0;
      uint4 v0 = *(const uint4*)(vp);
      uint4 v1 = *(const uint4*)(vp + 1536/8*8);  // next s row (+1536 u16)
      const u16* p0 = (const u16*)&v0;
      const u16* p1 = (const u16*)&v1;
      for (int j = 0; j < 8; ++j){
        u32 wv = (u32)p0[j] | ((u32)p1[j] << 16);
        *(u32*)(VT + (c0+j)*64 + sp*2) = wv;
      }
    }
    __syncthreads();
    // S = Q . K^T  (rows t, cols s)
    f32x4 sacc[4] = {};
    for (int kk = 0; kk < 2; ++kk){
      int kof = kk*32 + hi*8;
      for (int sf = 0; sf < 4; ++sf){
        bf16x8 kf = *(const bf16x8*)(Ks + (sf*16 + la)*64 + kof);
        sacc[sf] = __builtin_amdgcn_mfma_f32_16x16x32_bf16(qf[kk], kf, sacc[sf], 0, 0, 0);
      }
    }
    // online softmax, per-row t = hi*4 + r within the wave's 16 rows
    float alpha[4];
    for (int r = 0; r < 4; ++r){
      float m = fmaxf(fmaxf(sacc[0][r], sacc[1][r]), fmaxf(sacc[2][r], sacc[3][r]));
      m = fmaxf(m, __shfl_xor(m, 1));
      m = fmaxf(m, __shfl_xor(m, 2));
      m = fmaxf(m, __shfl_xor(m, 4));
      m = fmaxf(m, __shfl_xor(m, 8));
      float mn = fmaxf(mrun[r], m);
      alpha[r] = exp2f((mrun[r] - mn) * LOG2E);
      mrun[r] = mn;
    }
    u16* Pw = P + w*1024;
    float rsum[4] = {0.f, 0.f, 0.f, 0.f};
    for (int sf = 0; sf < 4; ++sf)
      for (int r = 0; r < 4; ++r){
        float p = exp2f((sacc[sf][r] - mrun[r]) * LOG2E);
        rsum[r] += p;
        Pw[(hi*4 + r)*64 + sf*16 + la] = f2bf(p);
      }
    for (int r = 0; r < 4; ++r){
      float s = rsum[r];
      s += __shfl_xor(s, 1);
      s += __shfl_xor(s, 2);
      s += __shfl_xor(s, 4);
      s += __shfl_xor(s, 8);
      lrun[r] = lrun[r]*alpha[r] + s;
      oacc[0][r] *= alpha[r]; oacc[1][r] *= alpha[r];
      oacc[2][r] *= alpha[r]; oacc[3][r] *= alpha[r];
    }
    // O += P . V   (wave-private P: same-wave LDS RAW, no barrier needed)
    for (int kk = 0; kk < 2; ++kk){
      bf16x8 pa = *(const bf16x8*)(Pw + la*64 + kk*32 + hi*8);
      for (int cf = 0; cf < 4; ++cf){
        bf16x8 vb = *(const bf16x8*)(VT + (cf*16 + la)*64 + kk*32 + hi*8);
        oacc[cf] = __builtin_amdgcn_mfma_f32_16x16x32_bf16(pa, vb, oacc[cf], 0, 0, 0);
      }
    }
  }
  // epilogue: normalize, transpose via LDS, add residual, coalesced f32 write
  float inv[4];
  for (int r = 0; r < 4; ++r) inv[r] = 1.f / lrun[r];
  for (int cf = 0; cf < 4; ++cf)
    for (int r = 0; r < 4; ++r)
      a_t[(cf*16 + la)*66 + w*16 + hi*4 + r] = oacc[cf][r] * inv[r];
  __syncthreads();
  const float* xb = x   + ((size_t)b*512 + hd*64)*1024 + t0;
  float*       ob = out + ((size_t)b*512 + hd*64)*1024 + t0;
  for (int it = 0; it < 4; ++it){
    int idx = it*1024 + tid*4;
    int c = idx >> 6, t4 = idx & 63;
    f32x4 xv = *(const f32x4*)(xb + (size_t)c*1024 + t4);
    f32x4 rr;
    rr.x = xv.x + a_t[c*66 + t4+0];
    rr.y = xv.y + a_t[c*66 + t4+1];
    rr.z = xv.z + a_t[c*66 + t4+2];
    rr.w = xv.w + a_t[c*66 + t4+3];
    *(f32x4*)(ob + (size_t)c*1024 + t4) = rr;
  }
}

extern "C" void kernel_launch(void* const* d_in, const int* in_sizes, int n_in,
                              void* d_out, int out_size, void* d_ws, size_t ws_size,
                              hipStream_t stream){
  const float* x  = (const float*)d_in[0];
  const float* gw = (const float*)d_in[1];
  const float* gb = (const float*)d_in[2];
  const float* cw = (const float*)d_in[3];
  const float* cb = (const float*)d_in[4];
  float* out = (float*)d_out;
  char* ws = (char*)d_ws;
  // ws layout (total ~65.5 MB)
  float* stats = (float*)(ws + 0);                       // 1024 f32
  float* biasS = (float*)(ws + 4096);                    // 1536 f32
  u16*   wb    = (u16*)  (ws + 10240);                   // 1536x512 bf16
  u16*   ht    = (u16*)  (ws + 10240 + 1572864);         // 16x1024x512 bf16
  u16*   qkv   = (u16*)  (ws + 10240 + 1572864 + 16777216); // 16x1024x1536 bf16

  hipLaunchKernelGGL(gn_stats_k, dim3(512),    dim3(256), 0, stream, x, stats);
  hipLaunchKernelGGL(gn_apply_k, dim3(512),    dim3(256), 0, stream, x, gw, gb, stats, ht);
  hipLaunchKernelGGL(prep_w_k,   dim3(768),    dim3(256), 0, stream, cw, cb, wb, biasS);
  hipLaunchKernelGGL(gemm_k,     dim3(96, 16), dim3(256), 0, stream, ht, wb, biasS, qkv);
  hipLaunchKernelGGL(attn_k,     dim3(2048),   dim3(256), 0, stream, qkv, x, out);
}

// Round 4
// 282.688 us; speedup vs baseline: 1.1235x; 1.1235x over previous
//
#include <hip/hip_runtime.h>
#include <hip/hip_bf16.h>

typedef unsigned short u16;
typedef unsigned int u32;
typedef __bf16 bf16x8 __attribute__((ext_vector_type(8)));
typedef float f32x4 __attribute__((ext_vector_type(4)));

__device__ __forceinline__ u16 f2bf(float f){
  u32 x = __float_as_uint(f);
  x += 0x7fffu + ((x >> 16) & 1u);   // RTNE
  return (u16)(x >> 16);
}

// async global->LDS 16B (m97/m193). LDS dest linear in lane order.
__device__ __forceinline__ void gload16(const void* g, void* l){
  __builtin_amdgcn_global_load_lds((const __attribute__((address_space(1))) u32*)g,
                                   (__attribute__((address_space(3))) u32*)l, 16, 0, 0);
}

// ---------------- GroupNorm stats: one block per (b, group) -----------------
__global__ __launch_bounds__(256) void gn_stats_k(const float* __restrict__ x,
                                                  float* __restrict__ stats){
  int blk = blockIdx.x;                 // b*32 + g
  const float* p = x + (size_t)blk * 16384;
  int tid = threadIdx.x;
  float s = 0.f, ss = 0.f;
  for (int it = 0; it < 16; ++it){
    f32x4 v = *(const f32x4*)(p + it*1024 + tid*4);
    s  += v.x + v.y + v.z + v.w;
    ss += v.x*v.x + v.y*v.y + v.z*v.z + v.w*v.w;
  }
  __shared__ float rs[256], rss[256];
  rs[tid] = s; rss[tid] = ss; __syncthreads();
  for (int st = 128; st > 0; st >>= 1){
    if (tid < st){ rs[tid] += rs[tid+st]; rss[tid] += rss[tid+st]; }
    __syncthreads();
  }
  if (tid == 0){
    float mean = rs[0] * (1.f/16384.f);
    float var  = rss[0] * (1.f/16384.f) - mean*mean;
    stats[blk*2]   = mean;
    stats[blk*2+1] = rsqrtf(var + 1e-5f);
  }
}

// ------- GroupNorm apply + transpose: ht[b][l][c] bf16 (c contiguous) -------
#define TP 520   // padded row stride (1040B = 260 dwords; 260%32=4 -> conflict-free; 16B aligned)
__global__ __launch_bounds__(256) void gn_apply_k(const float* __restrict__ x,
                                                  const float* __restrict__ gw,
                                                  const float* __restrict__ gb,
                                                  const float* __restrict__ stats,
                                                  u16* __restrict__ ht){
  int blk = blockIdx.x; int b = blk >> 5, lc = blk & 31;
  int tid = threadIdx.x;
  __shared__ float sm[32], sr[32], sgw[512], sgb[512];
  __shared__ u16 T[32*TP];              // [l][c] padded
  if (tid < 32){ sm[tid] = stats[(b*32+tid)*2]; sr[tid] = stats[(b*32+tid)*2+1]; }
  sgw[tid] = gw[tid]; sgw[tid+256] = gw[tid+256];
  sgb[tid] = gb[tid]; sgb[tid+256] = gb[tid+256];
  __syncthreads();
  const float* xb = x + (size_t)b*512*1024 + lc*32;
  for (int it = 0; it < 16; ++it){
    int idx = it*1024 + tid*4;
    int c = idx >> 5, l0 = idx & 31;
    f32x4 v = *(const f32x4*)(xb + (size_t)c*1024 + l0);
    int g = c >> 4;
    float mu = sm[g], r = sr[g], w = sgw[c], bb = sgb[c];
    T[(l0+0)*TP + c] = f2bf((v.x-mu)*r*w + bb);
    T[(l0+1)*TP + c] = f2bf((v.y-mu)*r*w + bb);
    T[(l0+2)*TP + c] = f2bf((v.z-mu)*r*w + bb);
    T[(l0+3)*TP + c] = f2bf((v.w-mu)*r*w + bb);
  }
  __syncthreads();
  u16* hb = ht + ((size_t)b*1024 + lc*32)*512;
  for (int it = 0; it < 8; ++it){
    int chunk = it*256 + tid;
    int l = chunk >> 6, c8 = (chunk & 63)*8;
    *(uint4*)(hb + (size_t)l*512 + c8) = *(const uint4*)(T + l*TP + c8);
  }
}

// ---- weight prep: conv_w -> bf16; fold 64^-0.25 * sqrt(log2e) into q,k ----
__global__ __launch_bounds__(256) void prep_w_k(const float* __restrict__ cw,
                                                const float* __restrict__ cb,
                                                u16* __restrict__ wb,
                                                float* __restrict__ biasS){
  int gid = blockIdx.x*256 + threadIdx.x;
  const float SC = 0.35355339059327373f * 1.2011224087864498f; // ch^-.25 * sqrt(log2 e)
  int i4 = gid*4;
  int row = i4 >> 9;                          // 512 per row
  float s = (row < 1024) ? SC : 1.0f;         // q,k rows scaled; v unscaled
  f32x4 v = *(const f32x4*)(cw + i4);
  wb[i4+0] = f2bf(v.x*s); wb[i4+1] = f2bf(v.y*s);
  wb[i4+2] = f2bf(v.z*s); wb[i4+3] = f2bf(v.w*s);
  if (gid < 1536) biasS[gid] = cb[gid] * ((gid < 1024) ? SC : 1.0f);
}

// ------------- QKV GEMM: per batch M=1024(l) N=1536(o) K=512(c) ------------
// 128x128 tile, BK=64, 4 waves (2x2), full global_load_lds staging (4+4).
// nt<8 -> q,k rows into qkv[b][l][1024]; nt>=8 -> V rows TRANSPOSED into vt.
__global__ __launch_bounds__(256) void gemm_k(const u16* __restrict__ ht,
                                              const u16* __restrict__ wb,
                                              const float* __restrict__ biasS,
                                              u16* __restrict__ qkv,
                                              u16* __restrict__ vt){
  int b  = blockIdx.y;
  int mt = blockIdx.x & 7, nt = blockIdx.x >> 3;
  int m0 = mt*128, n0 = nt*128;
  int tid = threadIdx.x, lane = tid & 63, wid = tid >> 6;
  int wm = wid >> 1, wn = wid & 1;
  int la = lane & 15, hi = lane >> 4;
  __shared__ u16 As[128*64], Bs[128*64];      // row-major, k contiguous (linear)
  const u16* Ab = ht + (size_t)b*1024*512;
  f32x4 acc[4][4] = {};
  int row0 = tid >> 3, sl0 = tid & 7;
  for (int kt = 0; kt < 8; ++kt){
    const u16* asrc = Ab + (size_t)(m0+row0)*512 + kt*64 + sl0*8;
    const u16* bsrc = wb + (size_t)(n0+row0)*512 + kt*64 + sl0*8;
    #pragma unroll
    for (int i = 0; i < 4; ++i){              // rows row0 + i*32  (full 128 rows)
      gload16(asrc + (size_t)i*32*512, As + (size_t)(tid + i*256)*8);
      gload16(bsrc + (size_t)i*32*512, Bs + (size_t)(tid + i*256)*8);
    }
    __syncthreads();                          // drains vmcnt -> tiles ready
    #pragma unroll
    for (int kk = 0; kk < 2; ++kk){
      int ko = kk*32 + hi*8;
      bf16x8 af[4], bf[4];
      #pragma unroll
      for (int mi = 0; mi < 4; ++mi) af[mi] = *(const bf16x8*)(As + (wm*64 + mi*16 + la)*64 + ko);
      #pragma unroll
      for (int ni = 0; ni < 4; ++ni) bf[ni] = *(const bf16x8*)(Bs + (wn*64 + ni*16 + la)*64 + ko);
      #pragma unroll
      for (int mi = 0; mi < 4; ++mi)
        #pragma unroll
        for (int ni = 0; ni < 4; ++ni)
          acc[mi][ni] = __builtin_amdgcn_mfma_f32_16x16x32_bf16(af[mi], bf[ni], acc[mi][ni], 0, 0, 0);
    }
    __syncthreads();                          // protect tiles until all consumed
  }
  if (nt < 8){
    u16* qb = qkv + (size_t)b*1024*1024;
    #pragma unroll
    for (int ni = 0; ni < 4; ++ni){
      int o = n0 + wn*64 + ni*16 + la;
      float bias = biasS[o];
      #pragma unroll
      for (int mi = 0; mi < 4; ++mi){
        int l = m0 + wm*64 + mi*16 + hi*4;
        #pragma unroll
        for (int r = 0; r < 4; ++r)
          qb[(size_t)(l+r)*1024 + o] = f2bf(acc[mi][ni][r] + bias);
      }
    }
  } else {
    // transpose V 128x128 via LDS (two 64-row halves), coalesced store
    int cc0 = (nt-8)*128;
    u16* T = As;                              // 64 cc x 128 l (unswizzled, epilogue-only)
    for (int half = 0; half < 2; ++half){
      __syncthreads();
      if (wn == half){
        #pragma unroll
        for (int ni = 0; ni < 4; ++ni){
          int cc = ni*16 + la;
          float bias = biasS[1024 + cc0 + half*64 + cc];
          #pragma unroll
          for (int mi = 0; mi < 4; ++mi){
            int l0 = wm*64 + mi*16 + hi*4;
            T[cc*128 + l0 + 0] = f2bf(acc[mi][ni][0] + bias);
            T[cc*128 + l0 + 1] = f2bf(acc[mi][ni][1] + bias);
            T[cc*128 + l0 + 2] = f2bf(acc[mi][ni][2] + bias);
            T[cc*128 + l0 + 3] = f2bf(acc[mi][ni][3] + bias);
          }
        }
      }
      __syncthreads();
      for (int it = 0; it < 4; ++it){
        int chunk = it*256 + tid;
        int cc = chunk >> 4, sl = chunk & 15;
        uint4 vv = *(const uint4*)(T + cc*128 + sl*8);
        *(uint4*)(vt + (size_t)(b*512 + cc0 + half*64 + cc)*1024 + m0 + sl*8) = vv;
      }
    }
  }
}

// ------------------- fused flash attention + residual ----------------------
// one block per (bh, 64-row t-tile); 4 waves x 16 t-rows.
// K/V reg-staged -> XOR-swizzled ds_write_b128; conflict-free swizzled reads.
__global__ __launch_bounds__(256) void attn_k(const u16* __restrict__ qkv,
                                              const u16* __restrict__ vt,
                                              const float* __restrict__ x,
                                              float* __restrict__ out){
  int orig = blockIdx.x;
  int vid = (orig & 7)*256 + (orig >> 3);   // XCD-bijective swizzle (2048%8==0)
  int bh = vid >> 4, tt = vid & 15;
  int b = bh >> 3, hd = bh & 7;
  int t0 = tt*64;
  int tid = threadIdx.x, lane = tid & 63, w = tid >> 6;
  int la = lane & 15, hi = lane >> 4;
  __shared__ u16 smem[12288];               // 24KB: Ks[0,8K) Vs[8K,16K) P[16K,24K)
  char* Ks = (char*)smem;
  char* Vs = (char*)smem + 8192;
  char* Pw = (char*)smem + 16384 + w*2048;  // wave-private 16t x 64s bf16
  float* a_t = (float*)smem;                // epilogue alias (16.9KB)
  const u16* qb = qkv + (size_t)b*1024*1024;
  const u16* vg = vt + (size_t)bh*64*1024;
  bf16x8 qf[2];
  {
    const u16* qr = qb + (size_t)(t0 + w*16 + la)*1024 + hd*64;
    qf[0] = *(const bf16x8*)(qr + hi*8);
    qf[1] = *(const bf16x8*)(qr + 32 + hi*8);
  }
  float mrun[4], lrun[4];
  f32x4 oacc[4] = {};
  #pragma unroll
  for (int r = 0; r < 4; ++r){ mrun[r] = -1e30f; lrun[r] = 0.f; }
  int r0 = tid >> 3, sl0 = tid & 7;
  const u16* ksrc = qb + (size_t)r0*1024 + 512 + hd*64 + sl0*8;  // + s0*1024
  const u16* vsrc = vg + (size_t)r0*1024 + sl0*8;                 // + s0
  int wb0 = (r0*128 + sl0*16) ^ ((r0 & 7) << 4);  // swizzled write byte; rows r0, r0+32 share XOR
  uint4 kr0 = *(const uint4*)(ksrc);
  uint4 kr1 = *(const uint4*)(ksrc + 32*1024);
  uint4 vr0 = *(const uint4*)(vsrc);
  uint4 vr1 = *(const uint4*)(vsrc + 32*1024);
  for (int st = 0; st < 16; ++st){
    __syncthreads();                        // all waves done reading prev tile
    *(uint4*)(Ks + wb0)        = kr0;
    *(uint4*)(Ks + wb0 + 4096) = kr1;
    *(uint4*)(Vs + wb0)        = vr0;
    *(uint4*)(Vs + wb0 + 4096) = vr1;
    __syncthreads();                        // tile published
    if (st < 15){                           // prefetch next tile into regs (overlaps compute)
      int s1 = (st+1)*64;
      kr0 = *(const uint4*)(ksrc + (size_t)s1*1024);
      kr1 = *(const uint4*)(ksrc + (size_t)(s1+32)*1024);
      vr0 = *(const uint4*)(vsrc + s1);
      vr1 = *(const uint4*)(vsrc + 32*1024 + s1);
    }
    // S = Q.K^T (rows t, cols s); swizzled reads
    f32x4 sacc[4] = {};
    #pragma unroll
    for (int kk = 0; kk < 2; ++kk){
      #pragma unroll
      for (int sf = 0; sf < 4; ++sf){
        int row = sf*16 + la;
        bf16x8 kf = *(const bf16x8*)(Ks + row*128 + (((kk*4 + hi) ^ (la & 7))*16));
        sacc[sf] = __builtin_amdgcn_mfma_f32_16x16x32_bf16(qf[kk], kf, sacc[sf], 0, 0, 0);
      }
    }
    // online softmax (logits already in log2 units)
    float alpha[4];
    #pragma unroll
    for (int r = 0; r < 4; ++r){
      float m = fmaxf(fmaxf(sacc[0][r], sacc[1][r]), fmaxf(sacc[2][r], sacc[3][r]));
      m = fmaxf(m, __shfl_xor(m, 1));
      m = fmaxf(m, __shfl_xor(m, 2));
      m = fmaxf(m, __shfl_xor(m, 4));
      m = fmaxf(m, __shfl_xor(m, 8));
      float mn = fmaxf(mrun[r], m);
      alpha[r] = __builtin_amdgcn_exp2f(mrun[r] - mn);
      mrun[r] = mn;
    }
    float rsum[4] = {0.f,0.f,0.f,0.f};
    #pragma unroll
    for (int sf = 0; sf < 4; ++sf)
      #pragma unroll
      for (int r = 0; r < 4; ++r){
        float p = __builtin_amdgcn_exp2f(sacc[sf][r] - mrun[r]);
        rsum[r] += p;
        int t = hi*4 + r;
        *(u16*)(Pw + ((t*128 + (sf*16 + la)*2) ^ ((t & 7) << 4))) = f2bf(p);
      }
    #pragma unroll
    for (int r = 0; r < 4; ++r){
      float s = rsum[r];
      s += __shfl_xor(s, 1);
      s += __shfl_xor(s, 2);
      s += __shfl_xor(s, 4);
      s += __shfl_xor(s, 8);
      lrun[r] = lrun[r]*alpha[r] + s;
      oacc[0][r] *= alpha[r]; oacc[1][r] *= alpha[r];
      oacc[2][r] *= alpha[r]; oacc[3][r] *= alpha[r];
    }
    // O += P.V (wave-private P; compiler inserts lgkm waits)
    #pragma unroll
    for (int kk = 0; kk < 2; ++kk){
      bf16x8 pa = *(const bf16x8*)(Pw + la*128 + (((kk*4 + hi) ^ (la & 7))*16));
      #pragma unroll
      for (int cf = 0; cf < 4; ++cf){
        int row = cf*16 + la;
        bf16x8 vv = *(const bf16x8*)(Vs + row*128 + (((kk*4 + hi) ^ (la & 7))*16));
        oacc[cf] = __builtin_amdgcn_mfma_f32_16x16x32_bf16(pa, vv, oacc[cf], 0, 0, 0);
      }
    }
  }
  // epilogue: normalize, transpose via LDS (aliases staging bufs), residual, store
  float inv[4];
  #pragma unroll
  for (int r = 0; r < 4; ++r) inv[r] = 1.f / lrun[r];
  __syncthreads();                          // all LDS reads done
  #pragma unroll
  for (int cf = 0; cf < 4; ++cf)
    #pragma unroll
    for (int r = 0; r < 4; ++r)
      a_t[(cf*16 + la)*66 + w*16 + hi*4 + r] = oacc[cf][r] * inv[r];
  __syncthreads();
  const float* xb = x   + ((size_t)b*512 + hd*64)*1024 + t0;
  float*       ob = out + ((size_t)b*512 + hd*64)*1024 + t0;
  #pragma unroll
  for (int it = 0; it < 4; ++it){
    int idx = it*1024 + tid*4;
    int c = idx >> 6, t4 = idx & 63;
    f32x4 xv = *(const f32x4*)(xb + (size_t)c*1024 + t4);
    f32x4 rr;
    rr.x = xv.x + a_t[c*66 + t4+0];
    rr.y = xv.y + a_t[c*66 + t4+1];
    rr.z = xv.z + a_t[c*66 + t4+2];
    rr.w = xv.w + a_t[c*66 + t4+3];
    *(f32x4*)(ob + (size_t)c*1024 + t4) = rr;
  }
}

extern "C" void kernel_launch(void* const* d_in, const int* in_sizes, int n_in,
                              void* d_out, int out_size, void* d_ws, size_t ws_size,
                              hipStream_t stream){
  const float* x  = (const float*)d_in[0];
  const float* gw = (const float*)d_in[1];
  const float* gb = (const float*)d_in[2];
  const float* cw = (const float*)d_in[3];
  const float* cb = (const float*)d_in[4];
  float* out = (float*)d_out;
  char* ws = (char*)d_ws;
  float* stats = (float*)(ws + 0);                    // 1024 f32
  float* biasS = (float*)(ws + 4096);                 // 1536 f32
  u16*   wb    = (u16*)  (ws + 10240);                // 1536x512 bf16 (1.5MB)
  u16*   ht    = (u16*)  (ws + 1583104);              // 16x1024x512  (16MB)
  u16*   qkv   = (u16*)  (ws + 18360320);             // 16x1024x1024 q,k (32MB)
  u16*   vtp   = (u16*)  (ws + 51914752);             // 16x512x1024 V^T (16MB)

  hipLaunchKernelGGL(gn_stats_k, dim3(512),    dim3(256), 0, stream, x, stats);
  hipLaunchKernelGGL(gn_apply_k, dim3(512),    dim3(256), 0, stream, x, gw, gb, stats, ht);
  hipLaunchKernelGGL(prep_w_k,   dim3(768),    dim3(256), 0, stream, cw, cb, wb, biasS);
  hipLaunchKernelGGL(gemm_k,     dim3(96, 16), dim3(256), 0, stream, ht, wb, biasS, qkv, vtp);
  hipLaunchKernelGGL(attn_k,     dim3(2048),   dim3(256), 0, stream, qkv, vtp, x, out);
}

// Round 5
// 216.947 us; speedup vs baseline: 1.4639x; 1.3030x over previous
//
#include <hip/hip_runtime.h>
#include <hip/hip_bf16.h>

typedef unsigned short u16;
typedef unsigned int u32;
typedef __bf16 bf16x8 __attribute__((ext_vector_type(8)));
typedef float f32x4 __attribute__((ext_vector_type(4)));

__device__ __forceinline__ u16 f2bf(float f){
  __bf16 h = (__bf16)f;               // HW v_cvt_pk_bf16_f32, RTNE
  return __builtin_bit_cast(u16, h);
}

// async global->LDS 16B (m97/m193). LDS dest linear in lane order.
__device__ __forceinline__ void gload16(const void* g, void* l){
  __builtin_amdgcn_global_load_lds((const __attribute__((address_space(1))) u32*)g,
                                   (__attribute__((address_space(3))) u32*)l, 16, 0, 0);
}

// ---------------- GroupNorm stats: one block per (b, group) -----------------
__global__ __launch_bounds__(256) void gn_stats_k(const float* __restrict__ x,
                                                  float* __restrict__ stats){
  int blk = blockIdx.x;                 // b*32 + g
  const float* p = x + (size_t)blk * 16384;
  int tid = threadIdx.x;
  float s = 0.f, ss = 0.f;
  for (int it = 0; it < 16; ++it){
    f32x4 v = *(const f32x4*)(p + it*1024 + tid*4);
    s  += v.x + v.y + v.z + v.w;
    ss += v.x*v.x + v.y*v.y + v.z*v.z + v.w*v.w;
  }
  __shared__ float rs[256], rss[256];
  rs[tid] = s; rss[tid] = ss; __syncthreads();
  for (int st = 128; st > 0; st >>= 1){
    if (tid < st){ rs[tid] += rs[tid+st]; rss[tid] += rss[tid+st]; }
    __syncthreads();
  }
  if (tid == 0){
    float mean = rs[0] * (1.f/16384.f);
    float var  = rss[0] * (1.f/16384.f) - mean*mean;
    stats[blk*2]   = mean;
    stats[blk*2+1] = rsqrtf(var + 1e-5f);
  }
}

// ------- GroupNorm apply + transpose: ht[b][l][c] bf16 (c contiguous) -------
#define TP 520   // padded row stride (1040B = 260 dwords; 260%32=4 -> conflict-free; 16B aligned)
__global__ __launch_bounds__(256) void gn_apply_k(const float* __restrict__ x,
                                                  const float* __restrict__ gw,
                                                  const float* __restrict__ gb,
                                                  const float* __restrict__ stats,
                                                  u16* __restrict__ ht){
  int blk = blockIdx.x; int b = blk >> 5, lc = blk & 31;
  int tid = threadIdx.x;
  __shared__ float sm[32], sr[32], sgw[512], sgb[512];
  __shared__ u16 T[32*TP];              // [l][c] padded
  if (tid < 32){ sm[tid] = stats[(b*32+tid)*2]; sr[tid] = stats[(b*32+tid)*2+1]; }
  sgw[tid] = gw[tid]; sgw[tid+256] = gw[tid+256];
  sgb[tid] = gb[tid]; sgb[tid+256] = gb[tid+256];
  __syncthreads();
  const float* xb = x + (size_t)b*512*1024 + lc*32;
  for (int it = 0; it < 16; ++it){
    int idx = it*1024 + tid*4;
    int c = idx >> 5, l0 = idx & 31;
    f32x4 v = *(const f32x4*)(xb + (size_t)c*1024 + l0);
    int g = c >> 4;
    float mu = sm[g], r = sr[g], w = sgw[c], bb = sgb[c];
    T[(l0+0)*TP + c] = f2bf((v.x-mu)*r*w + bb);
    T[(l0+1)*TP + c] = f2bf((v.y-mu)*r*w + bb);
    T[(l0+2)*TP + c] = f2bf((v.z-mu)*r*w + bb);
    T[(l0+3)*TP + c] = f2bf((v.w-mu)*r*w + bb);
  }
  __syncthreads();
  u16* hb = ht + ((size_t)b*1024 + lc*32)*512;
  for (int it = 0; it < 8; ++it){
    int chunk = it*256 + tid;
    int l = chunk >> 6, c8 = (chunk & 63)*8;
    *(uint4*)(hb + (size_t)l*512 + c8) = *(const uint4*)(T + l*TP + c8);
  }
}

// ---- weight prep: conv_w -> bf16; fold 64^-0.25 * sqrt(log2e) into q,k ----
__global__ __launch_bounds__(256) void prep_w_k(const float* __restrict__ cw,
                                                const float* __restrict__ cb,
                                                u16* __restrict__ wb,
                                                float* __restrict__ biasS){
  int gid = blockIdx.x*256 + threadIdx.x;
  const float SC = 0.35355339059327373f * 1.2011224087864498f; // ch^-.25 * sqrt(log2 e)
  int i4 = gid*4;
  int row = i4 >> 9;                          // 512 per row
  float s = (row < 1024) ? SC : 1.0f;         // q,k rows scaled; v unscaled
  f32x4 v = *(const f32x4*)(cw + i4);
  wb[i4+0] = f2bf(v.x*s); wb[i4+1] = f2bf(v.y*s);
  wb[i4+2] = f2bf(v.z*s); wb[i4+3] = f2bf(v.w*s);
  if (gid < 1536) biasS[gid] = cb[gid] * ((gid < 1024) ? SC : 1.0f);
}

// ------------- QKV GEMM: per batch M=1024(l) N=1536(o) K=512(c) ------------
// 128x128 tile, BK=64, 4 waves (2x2), full global_load_lds staging (4+4).
// nt<8 -> q,k rows into qkv[b][l][1024]; nt>=8 -> V rows TRANSPOSED into vt.
__global__ __launch_bounds__(256) void gemm_k(const u16* __restrict__ ht,
                                              const u16* __restrict__ wb,
                                              const float* __restrict__ biasS,
                                              u16* __restrict__ qkv,
                                              u16* __restrict__ vt){
  int b  = blockIdx.y;
  int mt = blockIdx.x & 7, nt = blockIdx.x >> 3;
  int m0 = mt*128, n0 = nt*128;
  int tid = threadIdx.x, lane = tid & 63, wid = tid >> 6;
  int wm = wid >> 1, wn = wid & 1;
  int la = lane & 15, hi = lane >> 4;
  __shared__ u16 As[128*64], Bs[128*64];      // row-major, k contiguous (linear)
  const u16* Ab = ht + (size_t)b*1024*512;
  f32x4 acc[4][4] = {};
  int row0 = tid >> 3, sl0 = tid & 7;
  for (int kt = 0; kt < 8; ++kt){
    const u16* asrc = Ab + (size_t)(m0+row0)*512 + kt*64 + sl0*8;
    const u16* bsrc = wb + (size_t)(n0+row0)*512 + kt*64 + sl0*8;
    #pragma unroll
    for (int i = 0; i < 4; ++i){              // rows row0 + i*32  (full 128 rows)
      gload16(asrc + (size_t)i*32*512, As + (size_t)(tid + i*256)*8);
      gload16(bsrc + (size_t)i*32*512, Bs + (size_t)(tid + i*256)*8);
    }
    __syncthreads();                          // drains vmcnt -> tiles ready
    #pragma unroll
    for (int kk = 0; kk < 2; ++kk){
      int ko = kk*32 + hi*8;
      bf16x8 af[4], bf[4];
      #pragma unroll
      for (int mi = 0; mi < 4; ++mi) af[mi] = *(const bf16x8*)(As + (wm*64 + mi*16 + la)*64 + ko);
      #pragma unroll
      for (int ni = 0; ni < 4; ++ni) bf[ni] = *(const bf16x8*)(Bs + (wn*64 + ni*16 + la)*64 + ko);
      #pragma unroll
      for (int mi = 0; mi < 4; ++mi)
        #pragma unroll
        for (int ni = 0; ni < 4; ++ni)
          acc[mi][ni] = __builtin_amdgcn_mfma_f32_16x16x32_bf16(af[mi], bf[ni], acc[mi][ni], 0, 0, 0);
    }
    __syncthreads();                          // protect tiles until all consumed
  }
  if (nt < 8){
    u16* qb = qkv + (size_t)b*1024*1024;
    #pragma unroll
    for (int ni = 0; ni < 4; ++ni){
      int o = n0 + wn*64 + ni*16 + la;
      float bias = biasS[o];
      #pragma unroll
      for (int mi = 0; mi < 4; ++mi){
        int l = m0 + wm*64 + mi*16 + hi*4;
        #pragma unroll
        for (int r = 0; r < 4; ++r)
          qb[(size_t)(l+r)*1024 + o] = f2bf(acc[mi][ni][r] + bias);
      }
    }
  } else {
    // transpose V 128x128 via LDS (two 64-row halves), coalesced store
    int cc0 = (nt-8)*128;
    u16* T = As;                              // 64 cc x 128 l (unswizzled, epilogue-only)
    for (int half = 0; half < 2; ++half){
      __syncthreads();
      if (wn == half){
        #pragma unroll
        for (int ni = 0; ni < 4; ++ni){
          int cc = ni*16 + la;
          float bias = biasS[1024 + cc0 + half*64 + cc];
          #pragma unroll
          for (int mi = 0; mi < 4; ++mi){
            int l0 = wm*64 + mi*16 + hi*4;
            T[cc*128 + l0 + 0] = f2bf(acc[mi][ni][0] + bias);
            T[cc*128 + l0 + 1] = f2bf(acc[mi][ni][1] + bias);
            T[cc*128 + l0 + 2] = f2bf(acc[mi][ni][2] + bias);
            T[cc*128 + l0 + 3] = f2bf(acc[mi][ni][3] + bias);
          }
        }
      }
      __syncthreads();
      for (int it = 0; it < 4; ++it){
        int chunk = it*256 + tid;
        int cc = chunk >> 4, sl = chunk & 15;
        uint4 vv = *(const uint4*)(T + cc*128 + sl*8);
        *(uint4*)(vt + (size_t)(b*512 + cc0 + half*64 + cc)*1024 + m0 + sl*8) = vv;
      }
    }
  }
}

// ------------------- fused flash attention + residual ----------------------
// one block per (bh, 64-row t-tile); 4 waves x 16 t-rows.
// K/V reg-staged -> XOR-swizzled ds_write_b128; conflict-free swizzled reads.
// Softmax: defer-max (THR=8, T13) + per-lane deferred sum reduction.
__global__ __launch_bounds__(256) void attn_k(const u16* __restrict__ qkv,
                                              const u16* __restrict__ vt,
                                              const float* __restrict__ x,
                                              float* __restrict__ out){
  int orig = blockIdx.x;
  int vid = (orig & 7)*256 + (orig >> 3);   // XCD-bijective swizzle (2048%8==0)
  int bh = vid >> 4, tt = vid & 15;
  int b = bh >> 3, hd = bh & 7;
  int t0 = tt*64;
  int tid = threadIdx.x, lane = tid & 63, w = tid >> 6;
  int la = lane & 15, hi = lane >> 4;
  __shared__ u16 smem[12288];               // 24KB: Ks[0,8K) Vs[8K,16K) P[16K,24K)
  char* Ks = (char*)smem;
  char* Vs = (char*)smem + 8192;
  char* Pw = (char*)smem + 16384 + w*2048;  // wave-private 16t x 64s bf16
  float* a_t = (float*)smem;                // epilogue alias (16.9KB)
  const u16* qb = qkv + (size_t)b*1024*1024;
  const u16* vg = vt + (size_t)bh*64*1024;
  bf16x8 qf[2];
  {
    const u16* qr = qb + (size_t)(t0 + w*16 + la)*1024 + hd*64;
    qf[0] = *(const bf16x8*)(qr + hi*8);
    qf[1] = *(const bf16x8*)(qr + 32 + hi*8);
  }
  float mrun[4], lsum[4];
  f32x4 oacc[4] = {};
  #pragma unroll
  for (int r = 0; r < 4; ++r){ mrun[r] = -1e30f; lsum[r] = 0.f; }
  int r0 = tid >> 3, sl0 = tid & 7;
  const u16* ksrc = qb + (size_t)r0*1024 + 512 + hd*64 + sl0*8;  // + s0*1024
  const u16* vsrc = vg + (size_t)r0*1024 + sl0*8;                 // + s0
  int wb0 = (r0*128 + sl0*16) ^ ((r0 & 7) << 4);  // swizzled write byte; rows r0, r0+32 share XOR
  uint4 kr0 = *(const uint4*)(ksrc);
  uint4 kr1 = *(const uint4*)(ksrc + 32*1024);
  uint4 vr0 = *(const uint4*)(vsrc);
  uint4 vr1 = *(const uint4*)(vsrc + 32*1024);
  for (int st = 0; st < 16; ++st){
    __syncthreads();                        // all waves done reading prev tile
    *(uint4*)(Ks + wb0)        = kr0;
    *(uint4*)(Ks + wb0 + 4096) = kr1;
    *(uint4*)(Vs + wb0)        = vr0;
    *(uint4*)(Vs + wb0 + 4096) = vr1;
    __syncthreads();                        // tile published
    if (st < 15){                           // prefetch next tile into regs (overlaps compute)
      int s1 = (st+1)*64;
      kr0 = *(const uint4*)(ksrc + (size_t)s1*1024);
      kr1 = *(const uint4*)(ksrc + (size_t)(s1+32)*1024);
      vr0 = *(const uint4*)(vsrc + s1);
      vr1 = *(const uint4*)(vsrc + 32*1024 + s1);
    }
    // S = Q.K^T (rows t, cols s); swizzled reads
    f32x4 sacc[4] = {};
    #pragma unroll
    for (int kk = 0; kk < 2; ++kk){
      #pragma unroll
      for (int sf = 0; sf < 4; ++sf){
        int row = sf*16 + la;
        bf16x8 kf = *(const bf16x8*)(Ks + row*128 + (((kk*4 + hi) ^ (la & 7))*16));
        sacc[sf] = __builtin_amdgcn_mfma_f32_16x16x32_bf16(qf[kk], kf, sacc[sf], 0, 0, 0);
      }
    }
    // ---- online softmax with defer-max (THR=8 in log2 units) ----
    float pmax[4];
    #pragma unroll
    for (int r = 0; r < 4; ++r)
      pmax[r] = fmaxf(fmaxf(sacc[0][r], sacc[1][r]), fmaxf(sacc[2][r], sacc[3][r]));
    bool ok = (pmax[0] <= mrun[0]+8.f) & (pmax[1] <= mrun[1]+8.f) &
              (pmax[2] <= mrun[2]+8.f) & (pmax[3] <= mrun[3]+8.f);
    if (!__all((int)ok)){                   // wave-uniform branch: full reduce + rescale
      #pragma unroll
      for (int r = 0; r < 4; ++r){
        float m = pmax[r];
        m = fmaxf(m, __shfl_xor(m, 1));
        m = fmaxf(m, __shfl_xor(m, 2));
        m = fmaxf(m, __shfl_xor(m, 4));
        m = fmaxf(m, __shfl_xor(m, 8));
        float mn = fmaxf(mrun[r], m);
        float alpha = __builtin_amdgcn_exp2f(mrun[r] - mn);
        mrun[r] = mn;
        lsum[r] *= alpha;
        oacc[0][r] *= alpha; oacc[1][r] *= alpha;
        oacc[2][r] *= alpha; oacc[3][r] *= alpha;
      }
    }
    #pragma unroll
    for (int sf = 0; sf < 4; ++sf)
      #pragma unroll
      for (int r = 0; r < 4; ++r){
        float p = __builtin_amdgcn_exp2f(sacc[sf][r] - mrun[r]);  // bounded by 2^8
        lsum[r] += p;                        // per-lane partial (reduced once at end)
        int t = hi*4 + r;
        *(u16*)(Pw + ((t*128 + (sf*16 + la)*2) ^ ((t & 7) << 4))) = f2bf(p);
      }
    // O += P.V (wave-private P; compiler inserts lgkm waits)
    #pragma unroll
    for (int kk = 0; kk < 2; ++kk){
      bf16x8 pa = *(const bf16x8*)(Pw + la*128 + (((kk*4 + hi) ^ (la & 7))*16));
      #pragma unroll
      for (int cf = 0; cf < 4; ++cf){
        int row = cf*16 + la;
        bf16x8 vv = *(const bf16x8*)(Vs + row*128 + (((kk*4 + hi) ^ (la & 7))*16));
        oacc[cf] = __builtin_amdgcn_mfma_f32_16x16x32_bf16(pa, vv, oacc[cf], 0, 0, 0);
      }
    }
  }
  // epilogue: reduce deferred sums, normalize, transpose via LDS, residual, store
  float inv[4];
  #pragma unroll
  for (int r = 0; r < 4; ++r){
    float s = lsum[r];
    s += __shfl_xor(s, 1);
    s += __shfl_xor(s, 2);
    s += __shfl_xor(s, 4);
    s += __shfl_xor(s, 8);
    inv[r] = 1.f / s;
  }
  __syncthreads();                          // all LDS reads done
  #pragma unroll
  for (int cf = 0; cf < 4; ++cf)
    #pragma unroll
    for (int r = 0; r < 4; ++r)
      a_t[(cf*16 + la)*66 + w*16 + hi*4 + r] = oacc[cf][r] * inv[r];
  __syncthreads();
  const float* xb = x   + ((size_t)b*512 + hd*64)*1024 + t0;
  float*       ob = out + ((size_t)b*512 + hd*64)*1024 + t0;
  #pragma unroll
  for (int it = 0; it < 4; ++it){
    int idx = it*1024 + tid*4;
    int c = idx >> 6, t4 = idx & 63;
    f32x4 xv = *(const f32x4*)(xb + (size_t)c*1024 + t4);
    f32x4 rr;
    rr.x = xv.x + a_t[c*66 + t4+0];
    rr.y = xv.y + a_t[c*66 + t4+1];
    rr.z = xv.z + a_t[c*66 + t4+2];
    rr.w = xv.w + a_t[c*66 + t4+3];
    *(f32x4*)(ob + (size_t)c*1024 + t4) = rr;
  }
}

extern "C" void kernel_launch(void* const* d_in, const int* in_sizes, int n_in,
                              void* d_out, int out_size, void* d_ws, size_t ws_size,
                              hipStream_t stream){
  const float* x  = (const float*)d_in[0];
  const float* gw = (const float*)d_in[1];
  const float* gb = (const float*)d_in[2];
  const float* cw = (const float*)d_in[3];
  const float* cb = (const float*)d_in[4];
  float* out = (float*)d_out;
  char* ws = (char*)d_ws;
  float* stats = (float*)(ws + 0);                    // 1024 f32
  float* biasS = (float*)(ws + 4096);                 // 1536 f32
  u16*   wb    = (u16*)  (ws + 10240);                // 1536x512 bf16 (1.5MB)
  u16*   ht    = (u16*)  (ws + 1583104);              // 16x1024x512  (16MB)
  u16*   qkv   = (u16*)  (ws + 18360320);             // 16x1024x1024 q,k (32MB)
  u16*   vtp   = (u16*)  (ws + 51914752);             // 16x512x1024 V^T (16MB)

  hipLaunchKernelGGL(gn_stats_k, dim3(512),    dim3(256), 0, stream, x, stats);
  hipLaunchKernelGGL(gn_apply_k, dim3(512),    dim3(256), 0, stream, x, gw, gb, stats, ht);
  hipLaunchKernelGGL(prep_w_k,   dim3(768),    dim3(256), 0, stream, cw, cb, wb, biasS);
  hipLaunchKernelGGL(gemm_k,     dim3(96, 16), dim3(256), 0, stream, ht, wb, biasS, qkv, vtp);
  hipLaunchKernelGGL(attn_k,     dim3(2048),   dim3(256), 0, stream, qkv, vtp, x, out);
}